// Round 1
// baseline (462.624 us; speedup 1.0000x reference)
//
#include <hip/hip_runtime.h>
#include <hip/hip_bf16.h>
#include <math.h>

// Problem constants (fixed by setup_inputs): B=8, N=2048, C=128, TOP_K=512
// Key algebraic facts exploited (see analysis):
//  - adj = softmax(relu(GL GL^T)) + I > 0 everywhere  => att == e, GL unused.
//  - e[b,i,j] = leaky_relu(p_i + q_j) monotone in p_i => top-512 per column is
//    the top-512 of p[b,:] for every column => mask depends only on (b,i).
//  - Unselected rows: softmax(all-zeros) = uniform => relu(mean_j h[b,j,:]).
//  - Selected rows: exp(leaky_relu(p+q)) separates into e^p e^q (p+q>=0) and
//    e^{.01p} e^{.01q} (p+q<0); sort by q => suffix/prefix sums + bsearch.

#define B_ 8
#define N_ 2048
#define C_ 128
#define TOPK_ 512
#define NCH_ 32      // chunks per batch
#define CL_ 64       // chunk length (NCH_*CL_ == N_)

// ---------------- ws layout (floats) ----------------
#define H_OFF    ((size_t)0)
#define P_OFF    (H_OFF + (size_t)B_*N_*C_)
#define Q_OFF    (P_OFF + (size_t)B_*N_)
#define QS_OFF   (Q_OFF + (size_t)B_*N_)
#define US_OFF   (QS_OFF + (size_t)B_*N_)
#define VS_OFF   (US_OFF + (size_t)B_*N_)
#define SRT_OFF  (VS_OFF + (size_t)B_*N_)          // ints
#define RANK_OFF (SRT_OFF + (size_t)B_*N_)         // ints
#define SUL_OFF  (RANK_OFF + (size_t)B_*N_)
#define PVL_OFF  (SUL_OFF + (size_t)B_*N_*129)
#define TOTU_OFF (PVL_OFF + (size_t)B_*N_*129)
#define TOTV_OFF (TOTU_OFF + (size_t)B_*NCH_*129)
#define CSU_OFF  (TOTV_OFF + (size_t)B_*NCH_*129)
#define CPV_OFF  (CSU_OFF + (size_t)B_*(NCH_+1)*129)
#define MR_OFF   (CPV_OFF + (size_t)B_*(NCH_+1)*129)

// ---------------- K1: h = x@W (f32), p = h@a1, q = h@a2 ----------------
// 64 rows/block, 256 threads. Thread (cg = t&7, rp = t>>3) computes rows
// {2rp,2rp+1} x cols {4cg+32i+j : i<4, j<4}. Column mapping 4cg+32i makes the
// 8 lanes of a wave hit 8 distinct float4 bank groups -> conflict-free W reads.
__global__ __launch_bounds__(256) void k_gemm(const float* __restrict__ x,
                                              const float* __restrict__ W,
                                              const float* __restrict__ a,
                                              float* __restrict__ h,
                                              float* __restrict__ p,
                                              float* __restrict__ q) {
  __shared__ float Wl[64 * 128];       // k-chunk x cols, 32 KB
  __shared__ float xl[64 * 68];        // rows x (64+4 pad), 17 KB
  __shared__ float a1l[128], a2l[128];
  __shared__ float redp[64][8], redq[64][8];
  const int t = threadIdx.x;
  const int r0 = blockIdx.x * 64;
  if (t < 128) { a1l[t] = a[t]; a2l[t] = a[128 + t]; }
  const int cg = t & 7, rp = t >> 3;
  const int lr0 = rp * 2, lr1 = lr0 + 1;
  float acc0[16], acc1[16];
#pragma unroll
  for (int i = 0; i < 16; ++i) { acc0[i] = 0.f; acc1[i] = 0.f; }

  for (int kc = 0; kc < 2; ++kc) {
    __syncthreads();
    // stage W rows kc*64..+63 (2048 float4s)
    const float4* W4 = (const float4*)(W + (size_t)kc * 64 * 128);
    float4* Wl4 = (float4*)Wl;
#pragma unroll
    for (int i = 0; i < 8; ++i) Wl4[t + 256 * i] = W4[t + 256 * i];
    // stage x tile: 64 rows x 64 cols (1024 float4s), padded stride 17 f4
#pragma unroll
    for (int i = 0; i < 4; ++i) {
      int idx = t + 256 * i;
      int row = idx >> 4, c4i = idx & 15;
      float4 v = *(const float4*)(x + (size_t)(r0 + row) * 128 + kc * 64 + c4i * 4);
      ((float4*)xl)[row * 17 + c4i] = v;
    }
    __syncthreads();
    for (int k = 0; k < 64; ++k) {
      float xv0 = xl[lr0 * 68 + k];
      float xv1 = xl[lr1 * 68 + k];
      const float4* Wr = (const float4*)(Wl + k * 128);
#pragma unroll
      for (int i = 0; i < 4; ++i) {
        float4 w = Wr[cg + 8 * i];
        acc0[i * 4 + 0] = fmaf(xv0, w.x, acc0[i * 4 + 0]);
        acc0[i * 4 + 1] = fmaf(xv0, w.y, acc0[i * 4 + 1]);
        acc0[i * 4 + 2] = fmaf(xv0, w.z, acc0[i * 4 + 2]);
        acc0[i * 4 + 3] = fmaf(xv0, w.w, acc0[i * 4 + 3]);
        acc1[i * 4 + 0] = fmaf(xv1, w.x, acc1[i * 4 + 0]);
        acc1[i * 4 + 1] = fmaf(xv1, w.y, acc1[i * 4 + 1]);
        acc1[i * 4 + 2] = fmaf(xv1, w.z, acc1[i * 4 + 2]);
        acc1[i * 4 + 3] = fmaf(xv1, w.w, acc1[i * 4 + 3]);
      }
    }
  }
  // store h + p/q partials
  float pp0 = 0.f, qq0 = 0.f, pp1 = 0.f, qq1 = 0.f;
  size_t hb = (size_t)r0 * 128;
#pragma unroll
  for (int i = 0; i < 4; ++i) {
    int c0 = 4 * cg + 32 * i;
    float4 v0 = make_float4(acc0[i*4+0], acc0[i*4+1], acc0[i*4+2], acc0[i*4+3]);
    float4 v1 = make_float4(acc1[i*4+0], acc1[i*4+1], acc1[i*4+2], acc1[i*4+3]);
    *(float4*)(h + hb + (size_t)lr0 * 128 + c0) = v0;
    *(float4*)(h + hb + (size_t)lr1 * 128 + c0) = v1;
#pragma unroll
    for (int j = 0; j < 4; ++j) {
      int c = c0 + j;
      pp0 = fmaf(acc0[i*4+j], a1l[c], pp0);
      qq0 = fmaf(acc0[i*4+j], a2l[c], qq0);
      pp1 = fmaf(acc1[i*4+j], a1l[c], pp1);
      qq1 = fmaf(acc1[i*4+j], a2l[c], qq1);
    }
  }
  redp[lr0][cg] = pp0; redq[lr0][cg] = qq0;
  redp[lr1][cg] = pp1; redq[lr1][cg] = qq1;
  __syncthreads();
  if (t < 64) {
    float sp = 0.f, sq = 0.f;
#pragma unroll
    for (int i = 0; i < 8; ++i) { sp += redp[t][i]; sq += redq[t][i]; }
    p[r0 + t] = sp;
    q[r0 + t] = sq;
  }
}

// ---------------- K2: per-batch bitonic sort of q (ascending) ----------------
__global__ __launch_bounds__(1024) void k_sort(const float* __restrict__ q,
                                               float* __restrict__ q_s,
                                               float* __restrict__ u_s,
                                               float* __restrict__ v_s,
                                               int* __restrict__ srt) {
  __shared__ float v[N_];
  __shared__ int id[N_];
  const int b = blockIdx.x, t = threadIdx.x;
  v[t] = q[b * N_ + t];           id[t] = t;
  v[t + 1024] = q[b * N_ + t + 1024]; id[t + 1024] = t + 1024;
  __syncthreads();
  for (int k = 2; k <= N_; k <<= 1) {
    for (int j = k >> 1; j > 0; j >>= 1) {
      for (int e = t; e < N_; e += 1024) {
        int ixj = e ^ j;
        if (ixj > e) {
          bool up = ((e & k) == 0);
          float ve = v[e], vx = v[ixj];
          bool sw = up ? (ve > vx) : (ve < vx);
          if (sw) {
            v[e] = vx; v[ixj] = ve;
            int tmp = id[e]; id[e] = id[ixj]; id[ixj] = tmp;
          }
        }
      }
      __syncthreads();
    }
  }
  for (int e = t; e < N_; e += 1024) {
    float vv = v[e];
    q_s[b * N_ + e] = vv;
    u_s[b * N_ + e] = __expf(vv);
    v_s[b * N_ + e] = __expf(0.01f * vv);
    srt[b * N_ + e] = id[e];
  }
}

// ---------------- K3: exact rank of p (lax.top_k tie semantics) --------------
__global__ __launch_bounds__(256) void k_rank(const float* __restrict__ p,
                                              int* __restrict__ rank) {
  __shared__ float pl[N_];
  const int b = blockIdx.x >> 3, seg = blockIdx.x & 7, t = threadIdx.x;
  for (int i = t; i < N_; i += 256) pl[i] = p[b * N_ + i];
  __syncthreads();
  const int i = seg * 256 + t;
  const float val = pl[i];
  int cnt = 0;
  for (int j = 0; j < N_; ++j) {
    float pj = pl[j];
    cnt += (pj > val) || (pj == val && j < i);
  }
  rank[b * N_ + i] = cnt;
}

// ---------------- K4: per-batch relu(mean of h rows) ----------------
__global__ __launch_bounds__(256) void k_mean(const float* __restrict__ h,
                                              float* __restrict__ mrw) {
  __shared__ float part[256];
  const int b = blockIdx.x, t = threadIdx.x;
  const int c = t & 127, hh = t >> 7;
  const float* hb = h + (size_t)b * N_ * C_;
  float s = 0.f;
  for (int j = hh * 1024; j < hh * 1024 + 1024; ++j) s += hb[(size_t)j * C_ + c];
  part[t] = s;
  __syncthreads();
  if (t < 128)
    mrw[b * C_ + t] = fmaxf((part[t] + part[t + 128]) * (1.0f / (float)N_), 0.f);
}

// ---------------- K5: chunk-local suffix(u*h) / exclusive-prefix(v*h) --------
// 129 "columns": c<128 -> h column, c==128 -> scalar (h==1).
__global__ void k_scanA(const float* __restrict__ h, const float* __restrict__ u_s,
                        const float* __restrict__ v_s, const int* __restrict__ srt,
                        float* __restrict__ SUl, float* __restrict__ PVl,
                        float* __restrict__ totU, float* __restrict__ totV) {
  __shared__ float hl[CL_ * 128];
  __shared__ float ul[CL_], vl[CL_];
  __shared__ int sl[CL_];
  const int blk = blockIdx.x;
  const int b = blk >> 5, ch = blk & 31;
  const int t = threadIdx.x;
  const int base = b * N_ + ch * CL_;
  if (t < CL_) { ul[t] = u_s[base + t]; vl[t] = v_s[base + t]; sl[t] = srt[base + t]; }
  __syncthreads();
  if (t < 128) {
    for (int tt = 0; tt < CL_; ++tt)
      hl[tt * 128 + t] = h[((size_t)b * N_ + sl[tt]) * C_ + t];
  }
  // each thread only reads its own column -> no extra barrier needed
  if (t <= 128) {
    float run = 0.f;
    for (int tt = CL_ - 1; tt >= 0; --tt) {
      float hv = (t < 128) ? hl[tt * 128 + t] : 1.0f;
      run = fmaf(ul[tt], hv, run);
      SUl[((size_t)base + tt) * 129 + t] = run;
    }
    totU[((size_t)b * NCH_ + ch) * 129 + t] = run;
    float run2 = 0.f;
    for (int tt = 0; tt < CL_; ++tt) {
      PVl[((size_t)base + tt) * 129 + t] = run2;
      float hv = (t < 128) ? hl[tt * 128 + t] : 1.0f;
      run2 = fmaf(vl[tt], hv, run2);
    }
    totV[((size_t)b * NCH_ + ch) * 129 + t] = run2;
  }
}

// ---------------- K6: chunk-total suffix/prefix tables ----------------
__global__ void k_scanB(const float* __restrict__ totU, const float* __restrict__ totV,
                        float* __restrict__ CSU, float* __restrict__ CPV) {
  const int b = blockIdx.x, t = threadIdx.x;  // 129 threads
  float s = 0.f;
  CSU[((size_t)b * (NCH_ + 1) + NCH_) * 129 + t] = 0.f;
  for (int ch = NCH_ - 1; ch >= 0; --ch) {
    s += totU[((size_t)b * NCH_ + ch) * 129 + t];
    CSU[((size_t)b * (NCH_ + 1) + ch) * 129 + t] = s;
  }
  float s2 = 0.f;
  for (int ch = 0; ch < NCH_; ++ch) {
    CPV[((size_t)b * (NCH_ + 1) + ch) * 129 + t] = s2;
    s2 += totV[((size_t)b * NCH_ + ch) * 129 + t];
  }
  CPV[((size_t)b * (NCH_ + 1) + NCH_) * 129 + t] = s2;
}

// ---------------- K7: per-row combine + transposed store ----------------
__global__ __launch_bounds__(256) void k_out(const float* __restrict__ p,
                                             const float* __restrict__ q_s,
                                             const int* __restrict__ rank,
                                             const float* __restrict__ SUl,
                                             const float* __restrict__ PVl,
                                             const float* __restrict__ CSU,
                                             const float* __restrict__ CPV,
                                             const float* __restrict__ mrw,
                                             float* __restrict__ out) {
  __shared__ float qs_l[N_];
  __shared__ float res[64 * 129];   // padded -> conflict-light transpose
  __shared__ float mr[128];
  __shared__ float pl[64];
  __shared__ int rk[64];
  const int blk = blockIdx.x;
  const int b = blk >> 5, tile = blk & 31;
  const int t = threadIdx.x;
  const int i0 = tile * 64;
  for (int i = t; i < N_; i += 256) qs_l[i] = q_s[b * N_ + i];
  if (t < 128) mr[t] = mrw[b * C_ + t];
  if (t < 64) { pl[t] = p[b * N_ + i0 + t]; rk[t] = rank[b * N_ + i0 + t]; }
  __syncthreads();
  const int half = t >> 7, c = t & 127;
  for (int ii2 = 0; ii2 < 64; ii2 += 2) {
    int ii = ii2 + half;
    float pv = pl[ii];
    float outv;
    if (rk[ii] < TOPK_) {
      float thr = -pv;
      int lo = 0, hi = N_;
      while (lo < hi) { int mid = (lo + hi) >> 1; if (qs_l[mid] < thr) lo = mid + 1; else hi = mid; }
      float A = __expf(pv), Bv = __expf(0.01f * pv);
      float suc, sus, pvc, pvs;
      if (lo < N_) {
        int chn = lo >> 6;  // /CL_
        size_t ro = ((size_t)b * N_ + lo) * 129;
        size_t co = ((size_t)b * (NCH_ + 1) + chn) * 129;
        suc = SUl[ro + c] + CSU[co + 129 + c];
        sus = SUl[ro + 128] + CSU[co + 129 + 128];
        pvc = PVl[ro + c] + CPV[co + c];
        pvs = PVl[ro + 128] + CPV[co + 128];
      } else {
        size_t co = ((size_t)b * (NCH_ + 1) + NCH_) * 129;
        suc = 0.f; sus = 0.f;
        pvc = CPV[co + c];
        pvs = CPV[co + 128];
      }
      float D = fmaf(A, sus, Bv * pvs);
      outv = fmaxf(fmaf(A, suc, Bv * pvc) / D, 0.f);
    } else {
      outv = mr[c];
    }
    res[ii * 129 + c] = outv;
  }
  __syncthreads();
  // out[b][c][i] = res[i - i0][c]
#pragma unroll
  for (int pass = 0; pass < 8; ++pass) {
    int cc = (t >> 4) + pass * 16;
    int ii4 = (t & 15) * 4;
    float4 v;
    v.x = res[(ii4 + 0) * 129 + cc];
    v.y = res[(ii4 + 1) * 129 + cc];
    v.z = res[(ii4 + 2) * 129 + cc];
    v.w = res[(ii4 + 3) * 129 + cc];
    *(float4*)(out + ((size_t)(b * C_ + cc)) * N_ + i0 + ii4) = v;
  }
}

extern "C" void kernel_launch(void* const* d_in, const int* in_sizes, int n_in,
                              void* d_out, int out_size, void* d_ws, size_t ws_size,
                              hipStream_t stream) {
  (void)in_sizes; (void)n_in; (void)out_size; (void)ws_size;
  const float* x = (const float*)d_in[0];
  const float* W = (const float*)d_in[1];
  const float* a = (const float*)d_in[2];
  // d_in[3] (GL) is provably unused: adj > 0 everywhere.
  float* out = (float*)d_out;
  float* ws = (float*)d_ws;

  float* h    = ws + H_OFF;
  float* p    = ws + P_OFF;
  float* q    = ws + Q_OFF;
  float* q_s  = ws + QS_OFF;
  float* u_s  = ws + US_OFF;
  float* v_s  = ws + VS_OFF;
  int*   srt  = (int*)(ws + SRT_OFF);
  int*   rank = (int*)(ws + RANK_OFF);
  float* SUl  = ws + SUL_OFF;
  float* PVl  = ws + PVL_OFF;
  float* totU = ws + TOTU_OFF;
  float* totV = ws + TOTV_OFF;
  float* CSU  = ws + CSU_OFF;
  float* CPV  = ws + CPV_OFF;
  float* mrw  = ws + MR_OFF;

  k_gemm<<<dim3((B_ * N_) / 64), dim3(256), 0, stream>>>(x, W, a, h, p, q);
  k_sort<<<dim3(B_), dim3(1024), 0, stream>>>(q, q_s, u_s, v_s, srt);
  k_rank<<<dim3(B_ * 8), dim3(256), 0, stream>>>(p, rank);
  k_mean<<<dim3(B_), dim3(256), 0, stream>>>(h, mrw);
  k_scanA<<<dim3(B_ * NCH_), dim3(129), 0, stream>>>(h, u_s, v_s, srt, SUl, PVl, totU, totV);
  k_scanB<<<dim3(B_), dim3(129), 0, stream>>>(totU, totV, CSU, CPV);
  k_out<<<dim3(B_ * 32), dim3(256), 0, stream>>>(p, q_s, rank, SUl, PVl, CSU, CPV, mrw, out);
}

// Round 2
// 217.424 us; speedup vs baseline: 2.1277x; 2.1277x over previous
//
#include <hip/hip_runtime.h>
#include <hip/hip_bf16.h>
#include <math.h>

// Problem constants (fixed by setup_inputs): B=8, N=2048, C=128, TOP_K=512
// Key algebraic facts exploited (see analysis):
//  - adj = softmax(relu(GL GL^T)) + I > 0 everywhere  => att == e, GL unused.
//  - e[b,i,j] = leaky_relu(p_i + q_j) monotone in p_i => top-512 per column is
//    the top-512 of p[b,:] for every column => mask depends only on (b,i).
//  - Unselected rows: softmax(all-zeros) = uniform => relu(mean_j h[b,j,:]).
//  - Selected rows: exp(leaky_relu(p+q)) separates into e^p e^q (p+q>=0) and
//    e^{.01p} e^{.01q} (p+q<0); sort by q => suffix/prefix sums + bsearch.
//
// R1: k_mean was 252 us (8 blocks, 0.36% occupancy, scalar strided loads).
//     Replaced with 2-stage reduction: 256 blocks float4 partial sums + tiny
//     finalize. Floor is 8 MB read / ~5 TB/s ~= 2 us.

#define B_ 8
#define N_ 2048
#define C_ 128
#define TOPK_ 512
#define NCH_ 32      // chunks per batch
#define CL_ 64       // chunk length (NCH_*CL_ == N_)

// ---------------- ws layout (floats) ----------------
#define H_OFF    ((size_t)0)
#define P_OFF    (H_OFF + (size_t)B_*N_*C_)
#define Q_OFF    (P_OFF + (size_t)B_*N_)
#define QS_OFF   (Q_OFF + (size_t)B_*N_)
#define US_OFF   (QS_OFF + (size_t)B_*N_)
#define VS_OFF   (US_OFF + (size_t)B_*N_)
#define SRT_OFF  (VS_OFF + (size_t)B_*N_)          // ints
#define RANK_OFF (SRT_OFF + (size_t)B_*N_)         // ints
#define SUL_OFF  (RANK_OFF + (size_t)B_*N_)
#define PVL_OFF  (SUL_OFF + (size_t)B_*N_*129)
#define TOTU_OFF (PVL_OFF + (size_t)B_*N_*129)
#define TOTV_OFF (TOTU_OFF + (size_t)B_*NCH_*129)
#define CSU_OFF  (TOTV_OFF + (size_t)B_*NCH_*129)
#define CPV_OFF  (CSU_OFF + (size_t)B_*(NCH_+1)*129)
#define MR_OFF   (CPV_OFF + (size_t)B_*(NCH_+1)*129)
#define MPART_OFF (MR_OFF + (size_t)B_*C_)         // B*32*128 partial col sums

// ---------------- K1: h = x@W (f32), p = h@a1, q = h@a2 ----------------
// 64 rows/block, 256 threads. Thread (cg = t&7, rp = t>>3) computes rows
// {2rp,2rp+1} x cols {4cg+32i+j : i<4, j<4}. Column mapping 4cg+32i makes the
// 8 lanes of a wave hit 8 distinct float4 bank groups -> conflict-free W reads.
__global__ __launch_bounds__(256) void k_gemm(const float* __restrict__ x,
                                              const float* __restrict__ W,
                                              const float* __restrict__ a,
                                              float* __restrict__ h,
                                              float* __restrict__ p,
                                              float* __restrict__ q) {
  __shared__ float Wl[64 * 128];       // k-chunk x cols, 32 KB
  __shared__ float xl[64 * 68];        // rows x (64+4 pad), 17 KB
  __shared__ float a1l[128], a2l[128];
  __shared__ float redp[64][8], redq[64][8];
  const int t = threadIdx.x;
  const int r0 = blockIdx.x * 64;
  if (t < 128) { a1l[t] = a[t]; a2l[t] = a[128 + t]; }
  const int cg = t & 7, rp = t >> 3;
  const int lr0 = rp * 2, lr1 = lr0 + 1;
  float acc0[16], acc1[16];
#pragma unroll
  for (int i = 0; i < 16; ++i) { acc0[i] = 0.f; acc1[i] = 0.f; }

  for (int kc = 0; kc < 2; ++kc) {
    __syncthreads();
    // stage W rows kc*64..+63 (2048 float4s)
    const float4* W4 = (const float4*)(W + (size_t)kc * 64 * 128);
    float4* Wl4 = (float4*)Wl;
#pragma unroll
    for (int i = 0; i < 8; ++i) Wl4[t + 256 * i] = W4[t + 256 * i];
    // stage x tile: 64 rows x 64 cols (1024 float4s), padded stride 17 f4
#pragma unroll
    for (int i = 0; i < 4; ++i) {
      int idx = t + 256 * i;
      int row = idx >> 4, c4i = idx & 15;
      float4 v = *(const float4*)(x + (size_t)(r0 + row) * 128 + kc * 64 + c4i * 4);
      ((float4*)xl)[row * 17 + c4i] = v;
    }
    __syncthreads();
    for (int k = 0; k < 64; ++k) {
      float xv0 = xl[lr0 * 68 + k];
      float xv1 = xl[lr1 * 68 + k];
      const float4* Wr = (const float4*)(Wl + k * 128);
#pragma unroll
      for (int i = 0; i < 4; ++i) {
        float4 w = Wr[cg + 8 * i];
        acc0[i * 4 + 0] = fmaf(xv0, w.x, acc0[i * 4 + 0]);
        acc0[i * 4 + 1] = fmaf(xv0, w.y, acc0[i * 4 + 1]);
        acc0[i * 4 + 2] = fmaf(xv0, w.z, acc0[i * 4 + 2]);
        acc0[i * 4 + 3] = fmaf(xv0, w.w, acc0[i * 4 + 3]);
        acc1[i * 4 + 0] = fmaf(xv1, w.x, acc1[i * 4 + 0]);
        acc1[i * 4 + 1] = fmaf(xv1, w.y, acc1[i * 4 + 1]);
        acc1[i * 4 + 2] = fmaf(xv1, w.z, acc1[i * 4 + 2]);
        acc1[i * 4 + 3] = fmaf(xv1, w.w, acc1[i * 4 + 3]);
      }
    }
  }
  // store h + p/q partials
  float pp0 = 0.f, qq0 = 0.f, pp1 = 0.f, qq1 = 0.f;
  size_t hb = (size_t)r0 * 128;
#pragma unroll
  for (int i = 0; i < 4; ++i) {
    int c0 = 4 * cg + 32 * i;
    float4 v0 = make_float4(acc0[i*4+0], acc0[i*4+1], acc0[i*4+2], acc0[i*4+3]);
    float4 v1 = make_float4(acc1[i*4+0], acc1[i*4+1], acc1[i*4+2], acc1[i*4+3]);
    *(float4*)(h + hb + (size_t)lr0 * 128 + c0) = v0;
    *(float4*)(h + hb + (size_t)lr1 * 128 + c0) = v1;
#pragma unroll
    for (int j = 0; j < 4; ++j) {
      int c = c0 + j;
      pp0 = fmaf(acc0[i*4+j], a1l[c], pp0);
      qq0 = fmaf(acc0[i*4+j], a2l[c], qq0);
      pp1 = fmaf(acc1[i*4+j], a1l[c], pp1);
      qq1 = fmaf(acc1[i*4+j], a2l[c], qq1);
    }
  }
  redp[lr0][cg] = pp0; redq[lr0][cg] = qq0;
  redp[lr1][cg] = pp1; redq[lr1][cg] = qq1;
  __syncthreads();
  if (t < 64) {
    float sp = 0.f, sq = 0.f;
#pragma unroll
    for (int i = 0; i < 8; ++i) { sp += redp[t][i]; sq += redq[t][i]; }
    p[r0 + t] = sp;
    q[r0 + t] = sq;
  }
}

// ---------------- K2: per-batch bitonic sort of q (ascending) ----------------
__global__ __launch_bounds__(1024) void k_sort(const float* __restrict__ q,
                                               float* __restrict__ q_s,
                                               float* __restrict__ u_s,
                                               float* __restrict__ v_s,
                                               int* __restrict__ srt) {
  __shared__ float v[N_];
  __shared__ int id[N_];
  const int b = blockIdx.x, t = threadIdx.x;
  v[t] = q[b * N_ + t];           id[t] = t;
  v[t + 1024] = q[b * N_ + t + 1024]; id[t + 1024] = t + 1024;
  __syncthreads();
  for (int k = 2; k <= N_; k <<= 1) {
    for (int j = k >> 1; j > 0; j >>= 1) {
      for (int e = t; e < N_; e += 1024) {
        int ixj = e ^ j;
        if (ixj > e) {
          bool up = ((e & k) == 0);
          float ve = v[e], vx = v[ixj];
          bool sw = up ? (ve > vx) : (ve < vx);
          if (sw) {
            v[e] = vx; v[ixj] = ve;
            int tmp = id[e]; id[e] = id[ixj]; id[ixj] = tmp;
          }
        }
      }
      __syncthreads();
    }
  }
  for (int e = t; e < N_; e += 1024) {
    float vv = v[e];
    q_s[b * N_ + e] = vv;
    u_s[b * N_ + e] = __expf(vv);
    v_s[b * N_ + e] = __expf(0.01f * vv);
    srt[b * N_ + e] = id[e];
  }
}

// ---------------- K3: exact rank of p (lax.top_k tie semantics) --------------
__global__ __launch_bounds__(256) void k_rank(const float* __restrict__ p,
                                              int* __restrict__ rank) {
  __shared__ float pl[N_];
  const int b = blockIdx.x >> 3, seg = blockIdx.x & 7, t = threadIdx.x;
  for (int i = t; i < N_; i += 256) pl[i] = p[b * N_ + i];
  __syncthreads();
  const int i = seg * 256 + t;
  const float val = pl[i];
  int cnt = 0;
  for (int j = 0; j < N_; ++j) {
    float pj = pl[j];
    cnt += (pj > val) || (pj == val && j < i);
  }
  rank[b * N_ + i] = cnt;
}

// ---------------- K4a: partial column sums of h, 64 rows per block -----------
// grid = B*32 blocks, 256 threads. Thread (c4 = t&31, hh = t>>5) reads rows
// hh + 8*j (j<8) as float4 -> fully coalesced 1 KB/wave-instr.
__global__ __launch_bounds__(256) void k_mean_part(const float* __restrict__ h,
                                                   float* __restrict__ mpart) {
  __shared__ float4 part[8][32];
  const int b = blockIdx.x >> 5, tile = blockIdx.x & 31;
  const int t = threadIdx.x;
  const int c4 = t & 31, hh = t >> 5;
  const float4* hb = (const float4*)(h + ((size_t)b * N_ + tile * 64) * C_);
  float4 s = make_float4(0.f, 0.f, 0.f, 0.f);
#pragma unroll
  for (int j = 0; j < 8; ++j) {
    float4 v = hb[(size_t)(hh + 8 * j) * 32 + c4];
    s.x += v.x; s.y += v.y; s.z += v.z; s.w += v.w;
  }
  part[hh][c4] = s;
  __syncthreads();
  if (t < 32) {
    float4 acc = part[0][t];
#pragma unroll
    for (int j = 1; j < 8; ++j) {
      float4 v = part[j][t];
      acc.x += v.x; acc.y += v.y; acc.z += v.z; acc.w += v.w;
    }
    *(float4*)(mpart + ((size_t)(b * 32 + tile)) * C_ + 4 * t) = acc;
  }
}

// ---------------- K4b: fold 32 partials -> relu(mean) ----------------
__global__ __launch_bounds__(128) void k_mean_fin(const float* __restrict__ mpart,
                                                  float* __restrict__ mrw) {
  const int b = blockIdx.x, t = threadIdx.x;
  float s = 0.f;
  for (int j = 0; j < 32; ++j) s += mpart[((size_t)(b * 32 + j)) * C_ + t];
  mrw[b * C_ + t] = fmaxf(s * (1.0f / (float)N_), 0.f);
}

// ---------------- K5: chunk-local suffix(u*h) / exclusive-prefix(v*h) --------
// 129 "columns": c<128 -> h column, c==128 -> scalar (h==1).
__global__ void k_scanA(const float* __restrict__ h, const float* __restrict__ u_s,
                        const float* __restrict__ v_s, const int* __restrict__ srt,
                        float* __restrict__ SUl, float* __restrict__ PVl,
                        float* __restrict__ totU, float* __restrict__ totV) {
  __shared__ float hl[CL_ * 128];
  __shared__ float ul[CL_], vl[CL_];
  __shared__ int sl[CL_];
  const int blk = blockIdx.x;
  const int b = blk >> 5, ch = blk & 31;
  const int t = threadIdx.x;
  const int base = b * N_ + ch * CL_;
  if (t < CL_) { ul[t] = u_s[base + t]; vl[t] = v_s[base + t]; sl[t] = srt[base + t]; }
  __syncthreads();
  if (t < 128) {
    for (int tt = 0; tt < CL_; ++tt)
      hl[tt * 128 + t] = h[((size_t)b * N_ + sl[tt]) * C_ + t];
  }
  // each thread only reads its own column -> no extra barrier needed
  if (t <= 128) {
    float run = 0.f;
    for (int tt = CL_ - 1; tt >= 0; --tt) {
      float hv = (t < 128) ? hl[tt * 128 + t] : 1.0f;
      run = fmaf(ul[tt], hv, run);
      SUl[((size_t)base + tt) * 129 + t] = run;
    }
    totU[((size_t)b * NCH_ + ch) * 129 + t] = run;
    float run2 = 0.f;
    for (int tt = 0; tt < CL_; ++tt) {
      PVl[((size_t)base + tt) * 129 + t] = run2;
      float hv = (t < 128) ? hl[tt * 128 + t] : 1.0f;
      run2 = fmaf(vl[tt], hv, run2);
    }
    totV[((size_t)b * NCH_ + ch) * 129 + t] = run2;
  }
}

// ---------------- K6: chunk-total suffix/prefix tables ----------------
__global__ void k_scanB(const float* __restrict__ totU, const float* __restrict__ totV,
                        float* __restrict__ CSU, float* __restrict__ CPV) {
  const int b = blockIdx.x, t = threadIdx.x;  // 129 threads
  float s = 0.f;
  CSU[((size_t)b * (NCH_ + 1) + NCH_) * 129 + t] = 0.f;
  for (int ch = NCH_ - 1; ch >= 0; --ch) {
    s += totU[((size_t)b * NCH_ + ch) * 129 + t];
    CSU[((size_t)b * (NCH_ + 1) + ch) * 129 + t] = s;
  }
  float s2 = 0.f;
  for (int ch = 0; ch < NCH_; ++ch) {
    CPV[((size_t)b * (NCH_ + 1) + ch) * 129 + t] = s2;
    s2 += totV[((size_t)b * NCH_ + ch) * 129 + t];
  }
  CPV[((size_t)b * (NCH_ + 1) + NCH_) * 129 + t] = s2;
}

// ---------------- K7: per-row combine + transposed store ----------------
__global__ __launch_bounds__(256) void k_out(const float* __restrict__ p,
                                             const float* __restrict__ q_s,
                                             const int* __restrict__ rank,
                                             const float* __restrict__ SUl,
                                             const float* __restrict__ PVl,
                                             const float* __restrict__ CSU,
                                             const float* __restrict__ CPV,
                                             const float* __restrict__ mrw,
                                             float* __restrict__ out) {
  __shared__ float qs_l[N_];
  __shared__ float res[64 * 129];   // padded -> conflict-light transpose
  __shared__ float mr[128];
  __shared__ float pl[64];
  __shared__ int rk[64];
  const int blk = blockIdx.x;
  const int b = blk >> 5, tile = blk & 31;
  const int t = threadIdx.x;
  const int i0 = tile * 64;
  for (int i = t; i < N_; i += 256) qs_l[i] = q_s[b * N_ + i];
  if (t < 128) mr[t] = mrw[b * C_ + t];
  if (t < 64) { pl[t] = p[b * N_ + i0 + t]; rk[t] = rank[b * N_ + i0 + t]; }
  __syncthreads();
  const int half = t >> 7, c = t & 127;
  for (int ii2 = 0; ii2 < 64; ii2 += 2) {
    int ii = ii2 + half;
    float pv = pl[ii];
    float outv;
    if (rk[ii] < TOPK_) {
      float thr = -pv;
      int lo = 0, hi = N_;
      while (lo < hi) { int mid = (lo + hi) >> 1; if (qs_l[mid] < thr) lo = mid + 1; else hi = mid; }
      float A = __expf(pv), Bv = __expf(0.01f * pv);
      float suc, sus, pvc, pvs;
      if (lo < N_) {
        int chn = lo >> 6;  // /CL_
        size_t ro = ((size_t)b * N_ + lo) * 129;
        size_t co = ((size_t)b * (NCH_ + 1) + chn) * 129;
        suc = SUl[ro + c] + CSU[co + 129 + c];
        sus = SUl[ro + 128] + CSU[co + 129 + 128];
        pvc = PVl[ro + c] + CPV[co + c];
        pvs = PVl[ro + 128] + CPV[co + 128];
      } else {
        size_t co = ((size_t)b * (NCH_ + 1) + NCH_) * 129;
        suc = 0.f; sus = 0.f;
        pvc = CPV[co + c];
        pvs = CPV[co + 128];
      }
      float D = fmaf(A, sus, Bv * pvs);
      outv = fmaxf(fmaf(A, suc, Bv * pvc) / D, 0.f);
    } else {
      outv = mr[c];
    }
    res[ii * 129 + c] = outv;
  }
  __syncthreads();
  // out[b][c][i] = res[i - i0][c]
#pragma unroll
  for (int pass = 0; pass < 8; ++pass) {
    int cc = (t >> 4) + pass * 16;
    int ii4 = (t & 15) * 4;
    float4 v;
    v.x = res[(ii4 + 0) * 129 + cc];
    v.y = res[(ii4 + 1) * 129 + cc];
    v.z = res[(ii4 + 2) * 129 + cc];
    v.w = res[(ii4 + 3) * 129 + cc];
    *(float4*)(out + ((size_t)(b * C_ + cc)) * N_ + i0 + ii4) = v;
  }
}

extern "C" void kernel_launch(void* const* d_in, const int* in_sizes, int n_in,
                              void* d_out, int out_size, void* d_ws, size_t ws_size,
                              hipStream_t stream) {
  (void)in_sizes; (void)n_in; (void)out_size; (void)ws_size;
  const float* x = (const float*)d_in[0];
  const float* W = (const float*)d_in[1];
  const float* a = (const float*)d_in[2];
  // d_in[3] (GL) is provably unused: adj > 0 everywhere.
  float* out = (float*)d_out;
  float* ws = (float*)d_ws;

  float* h    = ws + H_OFF;
  float* p    = ws + P_OFF;
  float* q    = ws + Q_OFF;
  float* q_s  = ws + QS_OFF;
  float* u_s  = ws + US_OFF;
  float* v_s  = ws + VS_OFF;
  int*   srt  = (int*)(ws + SRT_OFF);
  int*   rank = (int*)(ws + RANK_OFF);
  float* SUl  = ws + SUL_OFF;
  float* PVl  = ws + PVL_OFF;
  float* totU = ws + TOTU_OFF;
  float* totV = ws + TOTV_OFF;
  float* CSU  = ws + CSU_OFF;
  float* CPV  = ws + CPV_OFF;
  float* mrw  = ws + MR_OFF;
  float* mpart = ws + MPART_OFF;

  k_gemm<<<dim3((B_ * N_) / 64), dim3(256), 0, stream>>>(x, W, a, h, p, q);
  k_sort<<<dim3(B_), dim3(1024), 0, stream>>>(q, q_s, u_s, v_s, srt);
  k_rank<<<dim3(B_ * 8), dim3(256), 0, stream>>>(p, rank);
  k_mean_part<<<dim3(B_ * 32), dim3(256), 0, stream>>>(h, mpart);
  k_mean_fin<<<dim3(B_), dim3(128), 0, stream>>>(mpart, mrw);
  k_scanA<<<dim3(B_ * NCH_), dim3(129), 0, stream>>>(h, u_s, v_s, srt, SUl, PVl, totU, totV);
  k_scanB<<<dim3(B_), dim3(129), 0, stream>>>(totU, totV, CSU, CPV);
  k_out<<<dim3(B_ * 32), dim3(256), 0, stream>>>(p, q_s, rank, SUl, PVl, CSU, CPV, mrw, out);
}

// Round 3
// 169.941 us; speedup vs baseline: 2.7223x; 1.2794x over previous
//
#include <hip/hip_runtime.h>
#include <hip/hip_bf16.h>
#include <math.h>

// Problem constants (fixed by setup_inputs): B=8, N=2048, C=128, TOP_K=512
// Key algebraic facts exploited (see analysis):
//  - adj = softmax(relu(GL GL^T)) + I > 0 everywhere  => att == e, GL unused.
//  - e[b,i,j] = leaky_relu(p_i + q_j) monotone in p_i => top-512 per column is
//    the top-512 of p[b,:] for every column => mask depends only on (b,i).
//  - Unselected rows: softmax(all-zeros) = uniform => relu(mean_j h[b,j,:]).
//  - Selected rows: exp(leaky_relu(p+q)) separates into e^p e^q (p+q>=0) and
//    e^{.01p} e^{.01q} (p+q<0); sort by q => suffix/prefix sums + bsearch.
//
// R1: k_mean was 252 us (8 blocks, 0.36% occupancy). -> 2-stage reduction.
// R2: k_rank was 52.8 us (O(N^2) count, 64 blocks, latency-bound). Replaced
//     by threshold from a p-sort riding in k_sort's grid (8 extra blocks,
//     fully parallel with the q-sort blocks): selected iff
//     (p_i, -i) >= (p_sorted[511], -idx_511) lexicographically.

#define B_ 8
#define N_ 2048
#define C_ 128
#define TOPK_ 512
#define NCH_ 32      // chunks per batch
#define CL_ 64       // chunk length (NCH_*CL_ == N_)

// ---------------- ws layout (floats) ----------------
#define H_OFF    ((size_t)0)
#define P_OFF    (H_OFF + (size_t)B_*N_*C_)
#define Q_OFF    (P_OFF + (size_t)B_*N_)
#define QS_OFF   (Q_OFF + (size_t)B_*N_)
#define US_OFF   (QS_OFF + (size_t)B_*N_)
#define VS_OFF   (US_OFF + (size_t)B_*N_)
#define SRT_OFF  (VS_OFF + (size_t)B_*N_)          // ints
#define SUL_OFF  (SRT_OFF + (size_t)B_*N_)
#define PVL_OFF  (SUL_OFF + (size_t)B_*N_*129)
#define TOTU_OFF (PVL_OFF + (size_t)B_*N_*129)
#define TOTV_OFF (TOTU_OFF + (size_t)B_*NCH_*129)
#define CSU_OFF  (TOTV_OFF + (size_t)B_*NCH_*129)
#define CPV_OFF  (CSU_OFF + (size_t)B_*(NCH_+1)*129)
#define MR_OFF   (CPV_OFF + (size_t)B_*(NCH_+1)*129)
#define MPART_OFF (MR_OFF + (size_t)B_*C_)         // B*32*128 partial col sums
#define PTHR_OFF (MPART_OFF + (size_t)B_*32*C_)    // B floats
#define ITHR_OFF (PTHR_OFF + (size_t)B_)           // B ints

// ---------------- K1: h = x@W (f32), p = h@a1, q = h@a2 ----------------
// 64 rows/block, 256 threads. Thread (cg = t&7, rp = t>>3) computes rows
// {2rp,2rp+1} x cols {4cg+32i+j : i<4, j<4}. Column mapping 4cg+32i makes the
// 8 lanes of a wave hit 8 distinct float4 bank groups -> conflict-free W reads.
__global__ __launch_bounds__(256) void k_gemm(const float* __restrict__ x,
                                              const float* __restrict__ W,
                                              const float* __restrict__ a,
                                              float* __restrict__ h,
                                              float* __restrict__ p,
                                              float* __restrict__ q) {
  __shared__ float Wl[64 * 128];       // k-chunk x cols, 32 KB
  __shared__ float xl[64 * 68];        // rows x (64+4 pad), 17 KB
  __shared__ float a1l[128], a2l[128];
  __shared__ float redp[64][8], redq[64][8];
  const int t = threadIdx.x;
  const int r0 = blockIdx.x * 64;
  if (t < 128) { a1l[t] = a[t]; a2l[t] = a[128 + t]; }
  const int cg = t & 7, rp = t >> 3;
  const int lr0 = rp * 2, lr1 = lr0 + 1;
  float acc0[16], acc1[16];
#pragma unroll
  for (int i = 0; i < 16; ++i) { acc0[i] = 0.f; acc1[i] = 0.f; }

  for (int kc = 0; kc < 2; ++kc) {
    __syncthreads();
    // stage W rows kc*64..+63 (2048 float4s)
    const float4* W4 = (const float4*)(W + (size_t)kc * 64 * 128);
    float4* Wl4 = (float4*)Wl;
#pragma unroll
    for (int i = 0; i < 8; ++i) Wl4[t + 256 * i] = W4[t + 256 * i];
    // stage x tile: 64 rows x 64 cols (1024 float4s), padded stride 17 f4
#pragma unroll
    for (int i = 0; i < 4; ++i) {
      int idx = t + 256 * i;
      int row = idx >> 4, c4i = idx & 15;
      float4 v = *(const float4*)(x + (size_t)(r0 + row) * 128 + kc * 64 + c4i * 4);
      ((float4*)xl)[row * 17 + c4i] = v;
    }
    __syncthreads();
    for (int k = 0; k < 64; ++k) {
      float xv0 = xl[lr0 * 68 + k];
      float xv1 = xl[lr1 * 68 + k];
      const float4* Wr = (const float4*)(Wl + k * 128);
#pragma unroll
      for (int i = 0; i < 4; ++i) {
        float4 w = Wr[cg + 8 * i];
        acc0[i * 4 + 0] = fmaf(xv0, w.x, acc0[i * 4 + 0]);
        acc0[i * 4 + 1] = fmaf(xv0, w.y, acc0[i * 4 + 1]);
        acc0[i * 4 + 2] = fmaf(xv0, w.z, acc0[i * 4 + 2]);
        acc0[i * 4 + 3] = fmaf(xv0, w.w, acc0[i * 4 + 3]);
        acc1[i * 4 + 0] = fmaf(xv1, w.x, acc1[i * 4 + 0]);
        acc1[i * 4 + 1] = fmaf(xv1, w.y, acc1[i * 4 + 1]);
        acc1[i * 4 + 2] = fmaf(xv1, w.z, acc1[i * 4 + 2]);
        acc1[i * 4 + 3] = fmaf(xv1, w.w, acc1[i * 4 + 3]);
      }
    }
  }
  // store h + p/q partials
  float pp0 = 0.f, qq0 = 0.f, pp1 = 0.f, qq1 = 0.f;
  size_t hb = (size_t)r0 * 128;
#pragma unroll
  for (int i = 0; i < 4; ++i) {
    int c0 = 4 * cg + 32 * i;
    float4 v0 = make_float4(acc0[i*4+0], acc0[i*4+1], acc0[i*4+2], acc0[i*4+3]);
    float4 v1 = make_float4(acc1[i*4+0], acc1[i*4+1], acc1[i*4+2], acc1[i*4+3]);
    *(float4*)(h + hb + (size_t)lr0 * 128 + c0) = v0;
    *(float4*)(h + hb + (size_t)lr1 * 128 + c0) = v1;
#pragma unroll
    for (int j = 0; j < 4; ++j) {
      int c = c0 + j;
      pp0 = fmaf(acc0[i*4+j], a1l[c], pp0);
      qq0 = fmaf(acc0[i*4+j], a2l[c], qq0);
      pp1 = fmaf(acc1[i*4+j], a1l[c], pp1);
      qq1 = fmaf(acc1[i*4+j], a2l[c], qq1);
    }
  }
  redp[lr0][cg] = pp0; redq[lr0][cg] = qq0;
  redp[lr1][cg] = pp1; redq[lr1][cg] = qq1;
  __syncthreads();
  if (t < 64) {
    float sp = 0.f, sq = 0.f;
#pragma unroll
    for (int i = 0; i < 8; ++i) { sp += redp[t][i]; sq += redq[t][i]; }
    p[r0 + t] = sp;
    q[r0 + t] = sq;
  }
}

// ---------------- K2: per-batch bitonic sorts ----------------
// blocks 0..B_-1   : sort q[b] ascending (value, then index) -> q_s/u_s/v_s/srt
// blocks B_..2B_-1 : sort p[b] descending (value, then asc index) -> element
//                    511 = lax.top_k threshold (pthr, ithr).
__global__ __launch_bounds__(1024) void k_sort(const float* __restrict__ q,
                                               const float* __restrict__ p,
                                               float* __restrict__ q_s,
                                               float* __restrict__ u_s,
                                               float* __restrict__ v_s,
                                               int* __restrict__ srt,
                                               float* __restrict__ pthr,
                                               int* __restrict__ ithr) {
  __shared__ float v[N_];
  __shared__ int id[N_];
  const int blk = blockIdx.x, t = threadIdx.x;
  const bool isP = blk >= B_;
  const int b = isP ? blk - B_ : blk;
  const float* src = isP ? p : q;
  v[t] = src[b * N_ + t];               id[t] = t;
  v[t + 1024] = src[b * N_ + t + 1024]; id[t + 1024] = t + 1024;
  __syncthreads();
  for (int k = 2; k <= N_; k <<= 1) {
    for (int j = k >> 1; j > 0; j >>= 1) {
      for (int e = t; e < N_; e += 1024) {
        int ixj = e ^ j;
        if (ixj > e) {
          bool up = ((e & k) == 0);
          float ve = v[e], vx = v[ixj];
          int ide = id[e], idx_ = id[ixj];
          // prec: element e should precede element ixj in sorted order
          bool prec = isP ? (ve > vx || (ve == vx && ide < idx_))
                          : (ve < vx || (ve == vx && ide < idx_));
          bool sw = up ? !prec : prec;
          if (sw) {
            v[e] = vx; v[ixj] = ve;
            id[e] = idx_; id[ixj] = ide;
          }
        }
      }
      __syncthreads();
    }
  }
  if (isP) {
    if (t == 0) { pthr[b] = v[TOPK_ - 1]; ithr[b] = id[TOPK_ - 1]; }
  } else {
    for (int e = t; e < N_; e += 1024) {
      float vv = v[e];
      q_s[b * N_ + e] = vv;
      u_s[b * N_ + e] = __expf(vv);
      v_s[b * N_ + e] = __expf(0.01f * vv);
      srt[b * N_ + e] = id[e];
    }
  }
}

// ---------------- K4a: partial column sums of h, 64 rows per block -----------
// grid = B*32 blocks, 256 threads. Thread (c4 = t&31, hh = t>>5) reads rows
// hh + 8*j (j<8) as float4 -> fully coalesced 1 KB/wave-instr.
__global__ __launch_bounds__(256) void k_mean_part(const float* __restrict__ h,
                                                   float* __restrict__ mpart) {
  __shared__ float4 part[8][32];
  const int b = blockIdx.x >> 5, tile = blockIdx.x & 31;
  const int t = threadIdx.x;
  const int c4 = t & 31, hh = t >> 5;
  const float4* hb = (const float4*)(h + ((size_t)b * N_ + tile * 64) * C_);
  float4 s = make_float4(0.f, 0.f, 0.f, 0.f);
#pragma unroll
  for (int j = 0; j < 8; ++j) {
    float4 v = hb[(size_t)(hh + 8 * j) * 32 + c4];
    s.x += v.x; s.y += v.y; s.z += v.z; s.w += v.w;
  }
  part[hh][c4] = s;
  __syncthreads();
  if (t < 32) {
    float4 acc = part[0][t];
#pragma unroll
    for (int j = 1; j < 8; ++j) {
      float4 v = part[j][t];
      acc.x += v.x; acc.y += v.y; acc.z += v.z; acc.w += v.w;
    }
    *(float4*)(mpart + ((size_t)(b * 32 + tile)) * C_ + 4 * t) = acc;
  }
}

// ---------------- K4b: fold 32 partials -> relu(mean) ----------------
__global__ __launch_bounds__(128) void k_mean_fin(const float* __restrict__ mpart,
                                                  float* __restrict__ mrw) {
  const int b = blockIdx.x, t = threadIdx.x;
  float s = 0.f;
  for (int j = 0; j < 32; ++j) s += mpart[((size_t)(b * 32 + j)) * C_ + t];
  mrw[b * C_ + t] = fmaxf(s * (1.0f / (float)N_), 0.f);
}

// ---------------- K5: chunk-local suffix(u*h) / exclusive-prefix(v*h) --------
// 129 "columns": c<128 -> h column, c==128 -> scalar (h==1).
__global__ void k_scanA(const float* __restrict__ h, const float* __restrict__ u_s,
                        const float* __restrict__ v_s, const int* __restrict__ srt,
                        float* __restrict__ SUl, float* __restrict__ PVl,
                        float* __restrict__ totU, float* __restrict__ totV) {
  __shared__ float hl[CL_ * 128];
  __shared__ float ul[CL_], vl[CL_];
  __shared__ int sl[CL_];
  const int blk = blockIdx.x;
  const int b = blk >> 5, ch = blk & 31;
  const int t = threadIdx.x;
  const int base = b * N_ + ch * CL_;
  if (t < CL_) { ul[t] = u_s[base + t]; vl[t] = v_s[base + t]; sl[t] = srt[base + t]; }
  __syncthreads();
  if (t < 128) {
    for (int tt = 0; tt < CL_; ++tt)
      hl[tt * 128 + t] = h[((size_t)b * N_ + sl[tt]) * C_ + t];
  }
  // each thread only reads its own column -> no extra barrier needed
  if (t <= 128) {
    float run = 0.f;
    for (int tt = CL_ - 1; tt >= 0; --tt) {
      float hv = (t < 128) ? hl[tt * 128 + t] : 1.0f;
      run = fmaf(ul[tt], hv, run);
      SUl[((size_t)base + tt) * 129 + t] = run;
    }
    totU[((size_t)b * NCH_ + ch) * 129 + t] = run;
    float run2 = 0.f;
    for (int tt = 0; tt < CL_; ++tt) {
      PVl[((size_t)base + tt) * 129 + t] = run2;
      float hv = (t < 128) ? hl[tt * 128 + t] : 1.0f;
      run2 = fmaf(vl[tt], hv, run2);
    }
    totV[((size_t)b * NCH_ + ch) * 129 + t] = run2;
  }
}

// ---------------- K6: chunk-total suffix/prefix tables ----------------
__global__ void k_scanB(const float* __restrict__ totU, const float* __restrict__ totV,
                        float* __restrict__ CSU, float* __restrict__ CPV) {
  const int b = blockIdx.x, t = threadIdx.x;  // 129 threads
  float s = 0.f;
  CSU[((size_t)b * (NCH_ + 1) + NCH_) * 129 + t] = 0.f;
  for (int ch = NCH_ - 1; ch >= 0; --ch) {
    s += totU[((size_t)b * NCH_ + ch) * 129 + t];
    CSU[((size_t)b * (NCH_ + 1) + ch) * 129 + t] = s;
  }
  float s2 = 0.f;
  for (int ch = 0; ch < NCH_; ++ch) {
    CPV[((size_t)b * (NCH_ + 1) + ch) * 129 + t] = s2;
    s2 += totV[((size_t)b * NCH_ + ch) * 129 + t];
  }
  CPV[((size_t)b * (NCH_ + 1) + NCH_) * 129 + t] = s2;
}

// ---------------- K7: per-row combine + transposed store ----------------
__global__ __launch_bounds__(256) void k_out(const float* __restrict__ p,
                                             const float* __restrict__ q_s,
                                             const float* __restrict__ pthr,
                                             const int* __restrict__ ithr,
                                             const float* __restrict__ SUl,
                                             const float* __restrict__ PVl,
                                             const float* __restrict__ CSU,
                                             const float* __restrict__ CPV,
                                             const float* __restrict__ mrw,
                                             float* __restrict__ out) {
  __shared__ float qs_l[N_];
  __shared__ float res[64 * 129];   // padded -> conflict-light transpose
  __shared__ float mr[128];
  __shared__ float pl[64];
  const int blk = blockIdx.x;
  const int b = blk >> 5, tile = blk & 31;
  const int t = threadIdx.x;
  const int i0 = tile * 64;
  for (int i = t; i < N_; i += 256) qs_l[i] = q_s[b * N_ + i];
  if (t < 128) mr[t] = mrw[b * C_ + t];
  if (t < 64) pl[t] = p[b * N_ + i0 + t];
  const float thrv = pthr[b];
  const int thri = ithr[b];
  __syncthreads();
  const int half = t >> 7, c = t & 127;
  for (int ii2 = 0; ii2 < 64; ii2 += 2) {
    int ii = ii2 + half;
    float pv = pl[ii];
    float outv;
    bool keep = (pv > thrv) || (pv == thrv && (i0 + ii) <= thri);
    if (keep) {
      float thr = -pv;
      int lo = 0, hi = N_;
      while (lo < hi) { int mid = (lo + hi) >> 1; if (qs_l[mid] < thr) lo = mid + 1; else hi = mid; }
      float A = __expf(pv), Bv = __expf(0.01f * pv);
      float suc, sus, pvc, pvs;
      if (lo < N_) {
        int chn = lo >> 6;  // /CL_
        size_t ro = ((size_t)b * N_ + lo) * 129;
        size_t co = ((size_t)b * (NCH_ + 1) + chn) * 129;
        suc = SUl[ro + c] + CSU[co + 129 + c];
        sus = SUl[ro + 128] + CSU[co + 129 + 128];
        pvc = PVl[ro + c] + CPV[co + c];
        pvs = PVl[ro + 128] + CPV[co + 128];
      } else {
        size_t co = ((size_t)b * (NCH_ + 1) + NCH_) * 129;
        suc = 0.f; sus = 0.f;
        pvc = CPV[co + c];
        pvs = CPV[co + 128];
      }
      float D = fmaf(A, sus, Bv * pvs);
      outv = fmaxf(fmaf(A, suc, Bv * pvc) / D, 0.f);
    } else {
      outv = mr[c];
    }
    res[ii * 129 + c] = outv;
  }
  __syncthreads();
  // out[b][c][i] = res[i - i0][c]
#pragma unroll
  for (int pass = 0; pass < 8; ++pass) {
    int cc = (t >> 4) + pass * 16;
    int ii4 = (t & 15) * 4;
    float4 v;
    v.x = res[(ii4 + 0) * 129 + cc];
    v.y = res[(ii4 + 1) * 129 + cc];
    v.z = res[(ii4 + 2) * 129 + cc];
    v.w = res[(ii4 + 3) * 129 + cc];
    *(float4*)(out + ((size_t)(b * C_ + cc)) * N_ + i0 + ii4) = v;
  }
}

extern "C" void kernel_launch(void* const* d_in, const int* in_sizes, int n_in,
                              void* d_out, int out_size, void* d_ws, size_t ws_size,
                              hipStream_t stream) {
  (void)in_sizes; (void)n_in; (void)out_size; (void)ws_size;
  const float* x = (const float*)d_in[0];
  const float* W = (const float*)d_in[1];
  const float* a = (const float*)d_in[2];
  // d_in[3] (GL) is provably unused: adj > 0 everywhere.
  float* out = (float*)d_out;
  float* ws = (float*)d_ws;

  float* h    = ws + H_OFF;
  float* p    = ws + P_OFF;
  float* q    = ws + Q_OFF;
  float* q_s  = ws + QS_OFF;
  float* u_s  = ws + US_OFF;
  float* v_s  = ws + VS_OFF;
  int*   srt  = (int*)(ws + SRT_OFF);
  float* SUl  = ws + SUL_OFF;
  float* PVl  = ws + PVL_OFF;
  float* totU = ws + TOTU_OFF;
  float* totV = ws + TOTV_OFF;
  float* CSU  = ws + CSU_OFF;
  float* CPV  = ws + CPV_OFF;
  float* mrw  = ws + MR_OFF;
  float* mpart = ws + MPART_OFF;
  float* pthr = ws + PTHR_OFF;
  int*   ithr = (int*)(ws + ITHR_OFF);

  k_gemm<<<dim3((B_ * N_) / 64), dim3(256), 0, stream>>>(x, W, a, h, p, q);
  k_sort<<<dim3(2 * B_), dim3(1024), 0, stream>>>(q, p, q_s, u_s, v_s, srt, pthr, ithr);
  k_mean_part<<<dim3(B_ * 32), dim3(256), 0, stream>>>(h, mpart);
  k_mean_fin<<<dim3(B_), dim3(128), 0, stream>>>(mpart, mrw);
  k_scanA<<<dim3(B_ * NCH_), dim3(129), 0, stream>>>(h, u_s, v_s, srt, SUl, PVl, totU, totV);
  k_scanB<<<dim3(B_), dim3(129), 0, stream>>>(totU, totV, CSU, CPV);
  k_out<<<dim3(B_ * 32), dim3(256), 0, stream>>>(p, q_s, pthr, ithr, SUl, PVl, CSU, CPV, mrw, out);
}

// Round 4
// 119.894 us; speedup vs baseline: 3.8586x; 1.4174x over previous
//
#include <hip/hip_runtime.h>
#include <hip/hip_bf16.h>
#include <math.h>

// Problem constants (fixed by setup_inputs): B=8, N=2048, C=128, TOP_K=512
// Algebraic structure (verified passing since R1):
//  - adj = softmax(relu(GL GL^T)) + I > 0 everywhere  => att == e, GL unused.
//  - e[b,i,j] = leaky_relu(p_i + q_j) monotone in p_i => mask depends only on
//    (b,i): row kept iff (p_i, -i) >= 512th largest (p, -idx).
//  - Unselected rows: softmax(all-zeros) = uniform => relu(mean_j h[b,j,:]).
//  - Kept rows: exp(leaky_relu(p+q)) separates at q >= -p into e^p e^q and
//    e^{.01p} e^{.01q}; sort by q => suffix/prefix sums + bsearch per row.
//
// R1: k_mean 252us -> 2-stage reduction. R2: k_rank 52.8us -> threshold from
// p-sort riding k_sort's grid. R3: latency-bound structure overhaul:
//  - k_sort: u64-packed keys, thread owns pair (2t,2t+1): j=1 internal,
//    j<=64 wave shuffles (no barrier), j>=128 LDS (10 phases). Scalar
//    suffix/prefix scans (SUS/PVS) fused here (reversed-pack float2 scan).
//  - k_gemm: mean column-partials folded into epilogue (k_mean_part deleted).
//  - k_scanA: CL=32, 256-thread blocks, 128-wide coalesced SUl/PVl.
//  - k_fin: scanB + mean finalize merged. k_out: parallel bsearch phase,
//    per-row 1/D precomputed. 7 launches -> 5.

#define B_ 8
#define N_ 2048
#define C_ 128
#define TOPK_ 512
#define NCH_ 64      // chunks per batch
#define CL_ 32       // chunk length (NCH_*CL_ == N_)
#define NP1_ 2050    // padded N+1 stride (even -> float2-aligned)

// ---------------- ws layout (floats) ----------------
#define H_OFF    ((size_t)0)
#define P_OFF    (H_OFF + (size_t)B_*N_*C_)
#define Q_OFF    (P_OFF + (size_t)B_*N_)
#define QS_OFF   (Q_OFF + (size_t)B_*N_)
#define US_OFF   (QS_OFF + (size_t)B_*N_)
#define VS_OFF   (US_OFF + (size_t)B_*N_)
#define SRT_OFF  (VS_OFF + (size_t)B_*N_)          // ints
#define SUS_OFF  (SRT_OFF + (size_t)B_*N_)         // B*NP1_
#define PVS_OFF  (SUS_OFF + (size_t)B_*NP1_)       // B*NP1_
#define SUL_OFF  (PVS_OFF + (size_t)B_*NP1_)
#define PVL_OFF  (SUL_OFF + (size_t)B_*N_*128)
#define TOTU_OFF (PVL_OFF + (size_t)B_*N_*128)
#define TOTV_OFF (TOTU_OFF + (size_t)B_*NCH_*128)
#define CSU_OFF  (TOTV_OFF + (size_t)B_*NCH_*128)
#define CPV_OFF  (CSU_OFF + (size_t)B_*(NCH_+1)*128)
#define MR_OFF   (CPV_OFF + (size_t)B_*(NCH_+1)*128)
#define MPART_OFF (MR_OFF + (size_t)B_*C_)         // B*32*128 tile col sums
#define PTHR_OFF (MPART_OFF + (size_t)B_*32*C_)    // B floats
#define ITHR_OFF (PTHR_OFF + (size_t)B_)           // B ints

// monotone float <-> sortable uint
__device__ __forceinline__ unsigned enc_f(float f) {
  unsigned b = __float_as_uint(f);
  return b ^ ((b >> 31) ? 0xFFFFFFFFu : 0x80000000u);
}
__device__ __forceinline__ float dec_f(unsigned e) {
  unsigned b = (e & 0x80000000u) ? (e ^ 0x80000000u) : ~e;
  return __uint_as_float(b);
}
__device__ __forceinline__ unsigned long long sxor64(unsigned long long v, int m) {
  int lo = __shfl_xor((int)(unsigned)(v & 0xffffffffULL), m, 64);
  int hi = __shfl_xor((int)(unsigned)(v >> 32), m, 64);
  return (((unsigned long long)(unsigned)hi) << 32) | (unsigned)lo;
}

// ---------------- K1: h = x@W (f32), p = h@a1, q = h@a2, mean partials ------
__global__ __launch_bounds__(256) void k_gemm(const float* __restrict__ x,
                                              const float* __restrict__ W,
                                              const float* __restrict__ a,
                                              float* __restrict__ h,
                                              float* __restrict__ p,
                                              float* __restrict__ q,
                                              float* __restrict__ mpart) {
  __shared__ float Wl[64 * 128];       // 32 KB
  __shared__ float xl[64 * 68];        // 17 KB (reused as 32x128 scratch)
  __shared__ float a1l[128], a2l[128];
  __shared__ float redp[64][8], redq[64][8];
  const int t = threadIdx.x;
  const int r0 = blockIdx.x * 64;
  if (t < 128) { a1l[t] = a[t]; a2l[t] = a[128 + t]; }
  const int cg = t & 7, rp = t >> 3;
  const int lr0 = rp * 2, lr1 = lr0 + 1;
  float acc0[16], acc1[16];
#pragma unroll
  for (int i = 0; i < 16; ++i) { acc0[i] = 0.f; acc1[i] = 0.f; }

  for (int kc = 0; kc < 2; ++kc) {
    __syncthreads();
    const float4* W4 = (const float4*)(W + (size_t)kc * 64 * 128);
    float4* Wl4 = (float4*)Wl;
#pragma unroll
    for (int i = 0; i < 8; ++i) Wl4[t + 256 * i] = W4[t + 256 * i];
#pragma unroll
    for (int i = 0; i < 4; ++i) {
      int idx = t + 256 * i;
      int row = idx >> 4, c4i = idx & 15;
      float4 v = *(const float4*)(x + (size_t)(r0 + row) * 128 + kc * 64 + c4i * 4);
      ((float4*)xl)[row * 17 + c4i] = v;
    }
    __syncthreads();
    for (int k = 0; k < 64; ++k) {
      float xv0 = xl[lr0 * 68 + k];
      float xv1 = xl[lr1 * 68 + k];
      const float4* Wr = (const float4*)(Wl + k * 128);
#pragma unroll
      for (int i = 0; i < 4; ++i) {
        float4 w = Wr[cg + 8 * i];
        acc0[i * 4 + 0] = fmaf(xv0, w.x, acc0[i * 4 + 0]);
        acc0[i * 4 + 1] = fmaf(xv0, w.y, acc0[i * 4 + 1]);
        acc0[i * 4 + 2] = fmaf(xv0, w.z, acc0[i * 4 + 2]);
        acc0[i * 4 + 3] = fmaf(xv0, w.w, acc0[i * 4 + 3]);
        acc1[i * 4 + 0] = fmaf(xv1, w.x, acc1[i * 4 + 0]);
        acc1[i * 4 + 1] = fmaf(xv1, w.y, acc1[i * 4 + 1]);
        acc1[i * 4 + 2] = fmaf(xv1, w.z, acc1[i * 4 + 2]);
        acc1[i * 4 + 3] = fmaf(xv1, w.w, acc1[i * 4 + 3]);
      }
    }
  }
  // store h + p/q partials + mean column partials
  float pp0 = 0.f, qq0 = 0.f, pp1 = 0.f, qq1 = 0.f;
  size_t hb = (size_t)r0 * 128;
  __syncthreads();               // protect xl before scratch reuse
  float* scratch = xl;           // 32 x 128
#pragma unroll
  for (int i = 0; i < 4; ++i) {
    int c0 = 4 * cg + 32 * i;
    float4 v0 = make_float4(acc0[i*4+0], acc0[i*4+1], acc0[i*4+2], acc0[i*4+3]);
    float4 v1 = make_float4(acc1[i*4+0], acc1[i*4+1], acc1[i*4+2], acc1[i*4+3]);
    *(float4*)(h + hb + (size_t)lr0 * 128 + c0) = v0;
    *(float4*)(h + hb + (size_t)lr1 * 128 + c0) = v1;
#pragma unroll
    for (int j = 0; j < 4; ++j) {
      int c = c0 + j;
      scratch[rp * 128 + c] = acc0[i*4+j] + acc1[i*4+j];
      pp0 = fmaf(acc0[i*4+j], a1l[c], pp0);
      qq0 = fmaf(acc0[i*4+j], a2l[c], qq0);
      pp1 = fmaf(acc1[i*4+j], a1l[c], pp1);
      qq1 = fmaf(acc1[i*4+j], a2l[c], qq1);
    }
  }
  redp[lr0][cg] = pp0; redq[lr0][cg] = qq0;
  redp[lr1][cg] = pp1; redq[lr1][cg] = qq1;
  __syncthreads();
  if (t < 64) {
    float sp = 0.f, sq = 0.f;
#pragma unroll
    for (int i = 0; i < 8; ++i) { sp += redp[t][i]; sq += redq[t][i]; }
    p[r0 + t] = sp;
    q[r0 + t] = sq;
  }
  if (t < 128) {
    float s = 0.f;
#pragma unroll
    for (int rr = 0; rr < 32; ++rr) s += scratch[rr * 128 + t];
    mpart[(size_t)blockIdx.x * 128 + t] = s;
  }
}

// ---------------- K2: per-batch sorts + scalar scans ----------------
// blocks 0..B_-1   : sort q[b] asc (value, idx) -> q_s/u_s/v_s/srt + SUS/PVS
// blocks B_..2B_-1 : sort p[b] desc (value), asc idx -> pthr/ithr (rank 511)
__global__ __launch_bounds__(1024) void k_sort(const float* __restrict__ q,
                                               const float* __restrict__ p,
                                               float* __restrict__ q_s,
                                               float* __restrict__ u_s,
                                               float* __restrict__ v_s,
                                               int* __restrict__ srt,
                                               float* __restrict__ SUS,
                                               float* __restrict__ PVS,
                                               float* __restrict__ pthr,
                                               int* __restrict__ ithr) {
  __shared__ unsigned long long sh[N_];   // 16 KB
  __shared__ float2 sa[1024], sb[1024];   // 16 KB (q-blocks only)
  const int blk = blockIdx.x, t = threadIdx.x;
  const bool isP = blk >= B_;
  const int b = isP ? blk - B_ : blk;
  const float* src = isP ? p : q;
  float2 f2 = *(const float2*)(src + b * N_ + 2 * t);
  unsigned k0 = enc_f(f2.x), k1 = enc_f(f2.y);
  if (isP) { k0 = ~k0; k1 = ~k1; }
  unsigned long long r0 = ((unsigned long long)k0 << 32) | (unsigned)(2 * t);
  unsigned long long r1 = ((unsigned long long)k1 << 32) | (unsigned)(2 * t + 1);

  for (int k = 2; k <= N_; k <<= 1) {
    const bool up = (((2 * t) & k) == 0);
    int j = k >> 1;
    for (; j >= 128; j >>= 1) {           // cross-wave: LDS
      *(ulonglong2*)(sh + 2 * t) = make_ulonglong2(r0, r1);
      __syncthreads();
      int pe = (2 * t) ^ j;               // j even -> pe even, 16B aligned
      ulonglong2 pp = *(const ulonglong2*)(sh + pe);
      bool lower = (((2 * t) & j) == 0);
      bool kmin = (up == lower);
      r0 = kmin ? (r0 < pp.x ? r0 : pp.x) : (r0 > pp.x ? r0 : pp.x);
      r1 = kmin ? (r1 < pp.y ? r1 : pp.y) : (r1 > pp.y ? r1 : pp.y);
      __syncthreads();
    }
    for (; j >= 2; j >>= 1) {             // within-wave: shuffles, no barrier
      int j2 = j >> 1;
      unsigned long long p0 = sxor64(r0, j2);
      unsigned long long p1 = sxor64(r1, j2);
      bool lower = ((t & j2) == 0);
      bool kmin = (up == lower);
      r0 = kmin ? (r0 < p0 ? r0 : p0) : (r0 > p0 ? r0 : p0);
      r1 = kmin ? (r1 < p1 ? r1 : p1) : (r1 > p1 ? r1 : p1);
    }
    // j == 1: thread-internal
    if (up) {
      if (r0 > r1) { unsigned long long tm = r0; r0 = r1; r1 = tm; }
    } else {
      if (r1 > r0) { unsigned long long tm = r0; r0 = r1; r1 = tm; }
    }
  }

  if (isP) {
    if (t == 255) {  // element 511 = 2*255+1
      unsigned key = (unsigned)(r1 >> 32);
      pthr[b] = dec_f(~key);
      ithr[b] = (int)(unsigned)(r1 & 0xffffffffULL);
    }
    return;
  }
  // q path: outputs + fused scalar scans
  float v0 = dec_f((unsigned)(r0 >> 32));
  float v1 = dec_f((unsigned)(r1 >> 32));
  int i0 = (int)(unsigned)(r0 & 0xffffffffULL);
  int i1 = (int)(unsigned)(r1 & 0xffffffffULL);
  float u0 = __expf(v0), u1 = __expf(v1);
  float w0 = __expf(0.01f * v0), w1 = __expf(0.01f * v1);
  *(float2*)(q_s + b * N_ + 2 * t) = make_float2(v0, v1);
  *(float2*)(u_s + b * N_ + 2 * t) = make_float2(u0, u1);
  *(float2*)(v_s + b * N_ + 2 * t) = make_float2(w0, w1);
  *(int2*)(srt + b * N_ + 2 * t) = make_int2(i0, i1);
  // combined scan: x-component = pair-u reversed (suffix), y = pair-w (prefix)
  float pu = u0 + u1, pw = w0 + w1;
  sa[1023 - t].x = pu;
  sa[t].y = pw;
  __syncthreads();
  float2* cur = sa; float2* nxt = sb;
  for (int off = 1; off < 1024; off <<= 1) {
    float2 vv = cur[t];
    if (t >= off) { float2 o = cur[t - off]; vv.x += o.x; vv.y += o.y; }
    nxt[t] = vv;
    __syncthreads();
    float2* tmp = cur; cur = nxt; nxt = tmp;
  }
  float PSt = cur[1023 - t].x;   // suffix-inclusive of pair-u from pair t
  float PPt = cur[t].y;          // prefix-inclusive of pair-w through pair t
  *(float2*)(SUS + (size_t)b * NP1_ + 2 * t) = make_float2(PSt, PSt - u0);
  *(float2*)(PVS + (size_t)b * NP1_ + 2 * t) = make_float2(PPt - pw, PPt - w1);
  if (t == 1023) {
    SUS[(size_t)b * NP1_ + N_] = 0.f;
    PVS[(size_t)b * NP1_ + N_] = PPt;
  }
}

// ---------------- K3: chunk-local suffix(u*h) / exclusive-prefix(w*h) --------
// 2 chunks of CL_=32 per 256-thread block; 128-wide coalesced outputs.
__global__ __launch_bounds__(256) void k_scanA(const float* __restrict__ h,
                                               const float* __restrict__ u_s,
                                               const float* __restrict__ v_s,
                                               const int* __restrict__ srt,
                                               float* __restrict__ SUl,
                                               float* __restrict__ PVl,
                                               float* __restrict__ totU,
                                               float* __restrict__ totV) {
  __shared__ float hl[2][CL_][128];   // 32 KB
  __shared__ float ul[2][CL_], vl[2][CL_];
  __shared__ int sl[2][CL_];
  const int b = blockIdx.x >> 5, cp = blockIdx.x & 31;
  const int ch0 = cp * 2;
  const int t = threadIdx.x;
  if (t < 64) {
    int s2 = t >> 5, tt = t & 31;
    int gi = b * N_ + (ch0 + s2) * CL_ + tt;
    ul[s2][tt] = u_s[gi]; vl[s2][tt] = v_s[gi]; sl[s2][tt] = srt[gi];
  }
  __syncthreads();
  const int sub = t >> 7, c = t & 127;
  const int ch = ch0 + sub;
  const int base = b * N_ + ch * CL_;
  for (int tt = 0; tt < CL_; ++tt)
    hl[sub][tt][c] = h[((size_t)b * N_ + sl[sub][tt]) * 128 + c];
  float run = 0.f;
  for (int tt = CL_ - 1; tt >= 0; --tt) {
    run = fmaf(ul[sub][tt], hl[sub][tt][c], run);
    SUl[((size_t)(base + tt)) * 128 + c] = run;
  }
  totU[(size_t)(b * NCH_ + ch) * 128 + c] = run;
  float run2 = 0.f;
  for (int tt = 0; tt < CL_; ++tt) {
    PVl[((size_t)(base + tt)) * 128 + c] = run2;
    run2 = fmaf(vl[sub][tt], hl[sub][tt][c], run2);
  }
  totV[(size_t)(b * NCH_ + ch) * 128 + c] = run2;
}

// ---------------- K4: chunk-total tables + mean finalize ----------------
__global__ __launch_bounds__(256) void k_fin(const float* __restrict__ totU,
                                             const float* __restrict__ totV,
                                             const float* __restrict__ mpart,
                                             float* __restrict__ CSU,
                                             float* __restrict__ CPV,
                                             float* __restrict__ mrw) {
  const int b = blockIdx.x, t = threadIdx.x;
  if (t < 128) {
    float s = 0.f;
    CSU[((size_t)(b * (NCH_ + 1) + NCH_)) * 128 + t] = 0.f;
    for (int ch = NCH_ - 1; ch >= 0; --ch) {
      s += totU[(size_t)(b * NCH_ + ch) * 128 + t];
      CSU[((size_t)(b * (NCH_ + 1) + ch)) * 128 + t] = s;
    }
    float s2 = 0.f;
    for (int ch = 0; ch < NCH_; ++ch) {
      CPV[((size_t)(b * (NCH_ + 1) + ch)) * 128 + t] = s2;
      s2 += totV[(size_t)(b * NCH_ + ch) * 128 + t];
    }
    CPV[((size_t)(b * (NCH_ + 1) + NCH_)) * 128 + t] = s2;
  } else {
    int c = t - 128;
    float s = 0.f;
    for (int j2 = 0; j2 < 32; ++j2) s += mpart[(size_t)(b * 32 + j2) * 128 + c];
    mrw[b * 128 + c] = fmaxf(s * (1.0f / (float)N_), 0.f);
  }
}

// ---------------- K5: per-row combine + transposed store ----------------
__global__ __launch_bounds__(256) void k_out(const float* __restrict__ p,
                                             const float* __restrict__ q_s,
                                             const float* __restrict__ pthr,
                                             const int* __restrict__ ithr,
                                             const float* __restrict__ SUS,
                                             const float* __restrict__ PVS,
                                             const float* __restrict__ SUl,
                                             const float* __restrict__ PVl,
                                             const float* __restrict__ CSU,
                                             const float* __restrict__ CPV,
                                             const float* __restrict__ mrw,
                                             float* __restrict__ out) {
  __shared__ float qs_l[N_];        // 8 KB
  __shared__ float res[64 * 129];   // 33 KB
  __shared__ float mr[128];
  __shared__ float A_s[64], B_s[64], invD[64];
  __shared__ int lo_s[64], keep_s[64];
  const int b = blockIdx.x >> 5, tile = blockIdx.x & 31;
  const int t = threadIdx.x;
  const int i0 = tile * 64;
  for (int i = t; i < N_; i += 256) qs_l[i] = q_s[b * N_ + i];
  if (t < 128) mr[t] = mrw[b * 128 + t];
  __syncthreads();
  if (t < 64) {  // parallel bsearch + per-row scalars (once, not per lane)
    float pv = p[b * N_ + i0 + t];
    float thrv = pthr[b]; int thri = ithr[b];
    bool keep = (pv > thrv) || (pv == thrv && (i0 + t) <= thri);
    keep_s[t] = keep ? 1 : 0;
    float thr = -pv;
    int lo = 0, hi = N_;
    while (lo < hi) { int mid = (lo + hi) >> 1; if (qs_l[mid] < thr) lo = mid + 1; else hi = mid; }
    lo_s[t] = lo;
    float A = __expf(pv), Bv = __expf(0.01f * pv);
    A_s[t] = A; B_s[t] = Bv;
    float sus = SUS[(size_t)b * NP1_ + lo];
    float pvs = PVS[(size_t)b * NP1_ + lo];
    invD[t] = 1.0f / fmaf(A, sus, Bv * pvs);
  }
  __syncthreads();
  const int half = t >> 7, c = t & 127;
#pragma unroll 4
  for (int ii2 = 0; ii2 < 64; ii2 += 2) {
    int ii = ii2 + half;
    float outv;
    if (keep_s[ii]) {
      int lo = lo_s[ii];
      float A = A_s[ii], Bv = B_s[ii];
      float suc, pvc;
      if (lo < N_) {
        int chn = lo >> 5;   // / CL_
        size_t ro = ((size_t)(b * N_ + lo)) * 128;
        size_t cu = ((size_t)(b * (NCH_ + 1))) * 128;
        suc = SUl[ro + c] + CSU[cu + (size_t)(chn + 1) * 128 + c];
        pvc = PVl[ro + c] + CPV[cu + (size_t)chn * 128 + c];
      } else {
        suc = 0.f;
        pvc = CPV[((size_t)(b * (NCH_ + 1) + NCH_)) * 128 + c];
      }
      outv = fmaxf(fmaf(A, suc, Bv * pvc) * invD[ii], 0.f);
    } else {
      outv = mr[c];
    }
    res[ii * 129 + c] = outv;
  }
  __syncthreads();
  // out[b][c][i] = res[i - i0][c]
#pragma unroll
  for (int pass = 0; pass < 8; ++pass) {
    int cc = (t >> 4) + pass * 16;
    int ii4 = (t & 15) * 4;
    float4 v;
    v.x = res[(ii4 + 0) * 129 + cc];
    v.y = res[(ii4 + 1) * 129 + cc];
    v.z = res[(ii4 + 2) * 129 + cc];
    v.w = res[(ii4 + 3) * 129 + cc];
    *(float4*)(out + ((size_t)(b * C_ + cc)) * N_ + i0 + ii4) = v;
  }
}

extern "C" void kernel_launch(void* const* d_in, const int* in_sizes, int n_in,
                              void* d_out, int out_size, void* d_ws, size_t ws_size,
                              hipStream_t stream) {
  (void)in_sizes; (void)n_in; (void)out_size; (void)ws_size;
  const float* x = (const float*)d_in[0];
  const float* W = (const float*)d_in[1];
  const float* a = (const float*)d_in[2];
  // d_in[3] (GL) is provably unused: adj > 0 everywhere.
  float* out = (float*)d_out;
  float* ws = (float*)d_ws;

  float* h    = ws + H_OFF;
  float* p    = ws + P_OFF;
  float* q    = ws + Q_OFF;
  float* q_s  = ws + QS_OFF;
  float* u_s  = ws + US_OFF;
  float* v_s  = ws + VS_OFF;
  int*   srt  = (int*)(ws + SRT_OFF);
  float* SUS  = ws + SUS_OFF;
  float* PVS  = ws + PVS_OFF;
  float* SUl  = ws + SUL_OFF;
  float* PVl  = ws + PVL_OFF;
  float* totU = ws + TOTU_OFF;
  float* totV = ws + TOTV_OFF;
  float* CSU  = ws + CSU_OFF;
  float* CPV  = ws + CPV_OFF;
  float* mrw  = ws + MR_OFF;
  float* mpart = ws + MPART_OFF;
  float* pthr = ws + PTHR_OFF;
  int*   ithr = (int*)(ws + ITHR_OFF);

  k_gemm<<<dim3((B_ * N_) / 64), dim3(256), 0, stream>>>(x, W, a, h, p, q, mpart);
  k_sort<<<dim3(2 * B_), dim3(1024), 0, stream>>>(q, p, q_s, u_s, v_s, srt, SUS, PVS, pthr, ithr);
  k_scanA<<<dim3(B_ * NCH_ / 2), dim3(256), 0, stream>>>(h, u_s, v_s, srt, SUl, PVl, totU, totV);
  k_fin<<<dim3(B_), dim3(256), 0, stream>>>(totU, totV, mpart, CSU, CPV, mrw);
  k_out<<<dim3(B_ * 32), dim3(256), 0, stream>>>(p, q_s, pthr, ithr, SUS, PVS, SUl, PVl, CSU, CPV, mrw, out);
}